// Round 3
// baseline (183.167 us; speedup 1.0000x reference)
//
#include <hip/hip_runtime.h>
#include <hip/hip_bf16.h>

#define TASKS 16
#define DIM 1024
#define HID 128
#define NCLS 10
#define NB 65536
#define BM 64
#define NTILES (NB / BM + TASKS) // 1040 = 8 * 130, XCD-swizzle bijective

typedef __attribute__((ext_vector_type(8))) short bf16x8;
typedef __attribute__((ext_vector_type(4))) float f32x4;

__device__ __forceinline__ short f2bf(float f) {
    union { __hip_bfloat16 h; short s; } u; u.h = __float2bfloat16(f); return u.s;
}
__device__ __forceinline__ bf16x8 pack8(f32x4 a, f32x4 b) {
    bf16x8 r;
    r[0]=f2bf(a[0]); r[1]=f2bf(a[1]); r[2]=f2bf(a[2]); r[3]=f2bf(a[3]);
    r[4]=f2bf(b[0]); r[5]=f2bf(b[1]); r[6]=f2bf(b[2]); r[7]=f2bf(b[3]);
    return r;
}

// ws layout (ints): [0,16) cnt | [16,32) cursors | [64, 64+NB) rowIdx
// then (shorts): W1t [T][H][D] bf16 at ws+64+NB (4 MB), W2t [T][16][H] after (64 KB)

// ---- pass 1 (fused): histogram + W1/W2 transpose-to-bf16 ----
__global__ __launch_bounds__(256) void k_pre(const int* __restrict__ tid_arr,
                                             const float* __restrict__ W1,
                                             const float* __restrict__ W2,
                                             int* __restrict__ ws) {
    const int blk = blockIdx.x, tid = threadIdx.x;
    if (blk < 256) {                       // histogram
        __shared__ int l[TASKS];
        if (tid < TASKS) l[tid] = 0;
        __syncthreads();
        atomicAdd(&l[tid_arr[blk * 256 + tid]], 1);
        __syncthreads();
        if (tid < TASKS) atomicAdd(&ws[tid], l[tid]);
    } else if (blk < 512) {                // W1 [T][D][H] f32 -> W1t [T][H][D] bf16
        __shared__ float ld[64 * 129];
        const int b = blk - 256, t = b >> 4, dc = b & 15;
        const float* src = W1 + ((size_t)t * DIM + dc * 64) * HID;
        #pragma unroll
        for (int r = 0; r < 32; ++r) {
            int fl = r * 256 + tid, d = fl >> 7, h = fl & 127;
            ld[d * 129 + h] = src[fl];
        }
        __syncthreads();
        short* W1t = (short*)(ws + 64 + NB);
        #pragma unroll
        for (int r = 0; r < 32; ++r) {
            int fl = r * 256 + tid, h = fl >> 6, d = fl & 63;
            W1t[((size_t)t * HID + h) * DIM + dc * 64 + d] = f2bf(ld[d * 129 + h]);
        }
    } else {                               // W2 [T][H][C] f32 -> W2t [T][16][H] bf16 (pad C)
        const int t = blk - 512;
        short* W2t = (short*)(ws + 64 + NB) + (size_t)TASKS * HID * DIM;
        #pragma unroll
        for (int i = 0; i < 8; ++i) {
            int o = i * 256 + tid, c = o >> 7, h = o & 127;
            float v = (c < NCLS) ? W2[((size_t)t * HID + h) * NCLS + c] : 0.f;
            W2t[(t * 16 + c) * HID + h] = f2bf(v);
        }
    }
}

// ---- pass 2: scatter row indices grouped by task (offsets scanned inline) ----
__global__ __launch_bounds__(256) void k_scatter(const int* __restrict__ tid_arr,
                                                 int* __restrict__ ws) {
    __shared__ int l[TASKS], base[TASKS], off[TASKS];
    const int tid = threadIdx.x;
    if (tid < TASKS) l[tid] = 0;
    __syncthreads();
    const int i = blockIdx.x * 256 + tid;
    const int t = tid_arr[i];
    const int rank = atomicAdd(&l[t], 1);
    __syncthreads();
    if (tid == 0) {
        int ro = 0;
        for (int k = 0; k < TASKS; ++k) { off[k] = ro; ro += ws[k]; }
    }
    if (tid < TASKS && l[tid] > 0) base[tid] = atomicAdd(&ws[16 + tid], l[tid]);
    __syncthreads();
    ws[64 + off[t] + base[t] + rank] = i;
}

// ---- pass 3: fused grouped GEMM, barrier-free K-loop, direct-to-register ----
__global__ __launch_bounds__(256, 3) void k_main(
    const float* __restrict__ x, const float* __restrict__ b1,
    const float* __restrict__ b2, const int* __restrict__ ws,
    float* __restrict__ out)
{
    __shared__ int ridx[BM];
    __shared__ short hl[BM * HID];   // 16 KB, XOR-swizzled 256B rows

    const int* cnt = ws;
    const int* rowIdx = ws + 64;
    const short* W1t = (const short*)(ws + 64 + NB);
    const short* W2t = W1t + (size_t)TASKS * HID * DIM;

    // XCD-aware bijective swizzle: consecutive tiles (same task) cluster per XCD
    const int w = (blockIdx.x & 7) * (NTILES / 8) + (blockIdx.x >> 3);

    // inline scan of cnt -> (task, tile-in-task, row range)
    int t = -1, m = 0, gstart = 0;
    {
        int accT = 0, accOff = 0;
        for (int k = 0; k < TASKS; ++k) {
            const int c = cnt[k];
            const int nt = (c + BM - 1) >> 6;
            if (t < 0 && w < accT + nt) {
                const int tileInT = w - accT;
                t = k; gstart = accOff + tileInT * BM;
                m = c - tileInT * BM; if (m > BM) m = BM;
            }
            accT += nt; accOff += c;
        }
    }
    if (t < 0) return;

    const int tid = threadIdx.x;
    if (tid < BM) {
        const int rr = tid < m ? tid : m - 1;   // clamp: dup last row, stores masked
        ridx[tid] = rowIdx[gstart + rr];
    }
    __syncthreads();

    const int lane = tid & 63, wv = tid >> 6;
    const int lg = lane >> 4, lr = lane & 15;
    const int rowHalf = wv >> 1, colHalf = wv & 1;
    const int wrow = rowHalf * 32;

    const float* ap0 = x + ((size_t)ridx[wrow + lr] << 10) + lg * 8;
    const float* ap1 = x + ((size_t)ridx[wrow + 16 + lr] << 10) + lg * 8;
    const short* bp  = W1t + (((size_t)t * HID + colHalf * 64 + lr) << 10) + lg * 8;

    f32x4 acc[2][4] = {};
    f32x4 aA[2][2], aB[2][2];
    bf16x8 bA[4], bB[4];

    auto LOAD = [&](int kt, f32x4 (&a)[2][2], bf16x8 (&b)[4]) {
        const f32x4* p0 = (const f32x4*)(ap0 + kt * 32);
        const f32x4* p1 = (const f32x4*)(ap1 + kt * 32);
        a[0][0] = p0[0]; a[0][1] = p0[1];
        a[1][0] = p1[0]; a[1][1] = p1[1];
        #pragma unroll
        for (int cf = 0; cf < 4; ++cf)
            b[cf] = *(const bf16x8*)(bp + kt * 32 + cf * 16 * DIM);
    };
    auto COMP = [&](f32x4 (&a)[2][2], bf16x8 (&b)[4]) {
        bf16x8 af0 = pack8(a[0][0], a[0][1]);
        bf16x8 af1 = pack8(a[1][0], a[1][1]);
        #pragma unroll
        for (int cf = 0; cf < 4; ++cf) {
            acc[0][cf] = __builtin_amdgcn_mfma_f32_16x16x32_bf16(af0, b[cf], acc[0][cf], 0, 0, 0);
            acc[1][cf] = __builtin_amdgcn_mfma_f32_16x16x32_bf16(af1, b[cf], acc[1][cf], 0, 0, 0);
        }
    };

    LOAD(0, aA, bA);
    #pragma unroll
    for (int kt = 0; kt < 32; kt += 2) {
        LOAD(kt + 1, aB, bB);
        COMP(aA, bA);
        if (kt + 2 < 32) LOAD(kt + 2, aA, bA);
        COMP(aB, bB);
    }

    // epilogue: bias + relu, h quadrant -> swizzled LDS
    #pragma unroll
    for (int cf = 0; cf < 4; ++cf) {
        const int col = colHalf * 64 + cf * 16 + lr;
        const float b1v = b1[t * HID + col];
        const int ch = col >> 3;
        #pragma unroll
        for (int rf = 0; rf < 2; ++rf) {
            #pragma unroll
            for (int q = 0; q < 4; ++q) {
                const int row = wrow + rf * 16 + lg * 4 + q;
                const float hv = fmaxf(acc[rf][cf][q] + b1v, 0.f);
                hl[row * HID + ((ch ^ ((row & 7) << 1)) << 3) + (col & 7)] = f2bf(hv);
            }
        }
    }
    __syncthreads();

    // GEMM2: [64 x 128] * [128 x 16]; wave wv handles rows wv*16..+16
    const int row2 = wv * 16 + lr;
    f32x4 acc2 = {};
    #pragma unroll
    for (int ks = 0; ks < 4; ++ks) {
        bf16x8 avv = *(const bf16x8*)&hl[row2 * HID + (((ks * 4 + lg) ^ ((row2 & 7) << 1)) << 3)];
        bf16x8 bvv = *(const bf16x8*)(W2t + ((size_t)t * 16 + lr) * HID + ks * 32 + lg * 8);
        acc2 = __builtin_amdgcn_mfma_f32_16x16x32_bf16(avv, bvv, acc2, 0, 0, 0);
    }
    if (lr < NCLS) {
        const float b2v = b2[t * NCLS + lr];
        #pragma unroll
        for (int q = 0; q < 4; ++q) {
            const int row = wv * 16 + lg * 4 + q;
            if (row < m) out[(size_t)ridx[row] * NCLS + lr] = acc2[q] + b2v;
        }
    }
}

extern "C" void kernel_launch(void* const* d_in, const int* in_sizes, int n_in,
                              void* d_out, int out_size, void* d_ws, size_t ws_size,
                              hipStream_t stream) {
    (void)in_sizes; (void)n_in; (void)out_size; (void)ws_size;
    const float* x       = (const float*)d_in[0];
    const int*   task_id = (const int*)d_in[1];
    const float* W1      = (const float*)d_in[2];
    const float* b1      = (const float*)d_in[3];
    const float* W2      = (const float*)d_in[4];
    const float* b2      = (const float*)d_in[5];
    float* out = (float*)d_out;
    int* ws = (int*)d_ws;
    hipMemsetAsync(ws, 0, 128, stream);                 // zero cnt[16] + cursors[16]
    k_pre<<<528, 256, 0, stream>>>(task_id, W1, W2, ws);
    k_scatter<<<256, 256, 0, stream>>>(task_id, ws);
    k_main<<<NTILES, 256, 0, stream>>>(x, b1, b2, ws, out);
}

// Round 4
// 90.025 us; speedup vs baseline: 2.0346x; 2.0346x over previous
//
#include <hip/hip_runtime.h>
#include <hip/hip_bf16.h>

#define TASKS 16
#define DIM 1024
#define HID 128
#define NCLS 10
#define NB 65536
#define BM 128
#define NTILES (NB / BM + TASKS) // 528 = 8 * 66

typedef __attribute__((ext_vector_type(8))) short bf16x8;
typedef __attribute__((ext_vector_type(4))) float f32x4;
typedef __attribute__((ext_vector_type(2))) float f32x2;

__device__ __forceinline__ unsigned short f2bf(float f) {
    union { __hip_bfloat16 h; unsigned short s; } u; u.h = __float2bfloat16(f); return u.s;
}

// async global->LDS, 16B/lane: dst is WAVE-UNIFORM base (HW adds lane*16), src is per-lane
__device__ __forceinline__ void glds16(const void* gsrc, void* ldst) {
    __builtin_amdgcn_global_load_lds(
        (const __attribute__((address_space(1))) unsigned*)gsrc,
        (__attribute__((address_space(3))) unsigned*)ldst, 16, 0, 0);
}

// ws (ints): [0,16) cnt | [16,32) cursors | [64,64+NB) rowIdx
// shorts after: W1s [T][32 kstep][4096] bf16 swizzled-tile order (4MB), W2t [T][16][128] (64KB)

// ---- pass 1: histogram + W1 -> swizzled bf16 tiles + W2 transpose ----
__global__ __launch_bounds__(256) void k_pre(const int* __restrict__ tid_arr,
                                             const float* __restrict__ W1,
                                             const float* __restrict__ W2,
                                             int* __restrict__ ws) {
    const int blk = blockIdx.x, tid = threadIdx.x;
    if (blk < 256) {                           // histogram
        __shared__ int l[TASKS];
        if (tid < TASKS) l[tid] = 0;
        __syncthreads();
        atomicAdd(&l[tid_arr[blk * 256 + tid]], 1);
        __syncthreads();
        if (tid < TASKS) atomicAdd(&ws[tid], l[tid]);
    } else if (blk < 768) {                    // W1 -> W1s: 8KB tile per (t, kstep)
        const int idx = blk - 256;             // [0,512)
        const int t = idx >> 5, kt = idx & 31;
        char* dst = (char*)((short*)(ws + 64 + NB) + ((size_t)(t * 32 + kt) << 12));
        const float* wsrc = W1 + (size_t)t * DIM * HID;
        #pragma unroll
        for (int cch = 0; cch < 2; ++cch) {
            const int p = tid * 32 + cch * 16;            // byte pos in 8KB tile
            const int col = p >> 6;                       // h column (64B per col)
            const int lgk = ((p >> 4) & 3) ^ (col & 3);   // baked XOR swizzle
            const int kbase = kt * 32 + lgk * 8;
            bf16x8 v;
            #pragma unroll
            for (int j = 0; j < 8; ++j)
                v[j] = (short)f2bf(wsrc[(size_t)(kbase + j) * HID + col]);
            *(bf16x8*)(dst + p) = v;
        }
    } else {                                   // W2 [T][H][C] -> W2t [T][16][H] bf16
        const int t = blk - 768;
        short* W2t = (short*)(ws + 64 + NB) + ((size_t)TASKS * 32 * 4096);
        #pragma unroll
        for (int i = 0; i < 8; ++i) {
            const int o = i * 256 + tid, c = o >> 7, h = o & 127;
            const float v = (c < NCLS) ? W2[((size_t)t * HID + h) * NCLS + c] : 0.f;
            W2t[((size_t)t * 16 + c) * HID + h] = (short)f2bf(v);
        }
    }
}

// ---- pass 2: scatter row indices grouped by task ----
__global__ __launch_bounds__(256) void k_scatter(const int* __restrict__ tid_arr,
                                                 int* __restrict__ ws) {
    __shared__ int l[TASKS], base[TASKS], off[TASKS];
    const int tid = threadIdx.x;
    if (tid < TASKS) l[tid] = 0;
    __syncthreads();
    const int i = blockIdx.x * 256 + tid;
    const int t = tid_arr[i];
    const int rank = atomicAdd(&l[t], 1);
    __syncthreads();
    if (tid == 0) {
        int ro = 0;
        for (int k = 0; k < TASKS; ++k) { off[k] = ro; ro += ws[k]; }
    }
    if (tid < TASKS && l[tid] > 0) base[tid] = atomicAdd(&ws[16 + tid], l[tid]);
    __syncthreads();
    ws[64 + off[t] + base[t] + rank] = i;
}

// ---- pass 3: fused grouped GEMM, minimal-divergence staging ----
__global__ __launch_bounds__(256, 3) void k_main(
    const float* __restrict__ x, const float* __restrict__ b1,
    const float* __restrict__ b2, const int* __restrict__ ws,
    float* __restrict__ out)
{
    // [buf][A 8KB | B 8KB] x2 = 32KB; epilogue reuses all 32KB as hl[128][256B]
    __shared__ __align__(16) short smem[16384];
    __shared__ int ridx[BM];

    const int* cnt = ws;
    const int* rowIdx = ws + 64;
    const short* W1s = (const short*)(ws + 64 + NB);
    const short* W2t = W1s + ((size_t)TASKS * 32 * 4096);

    // XCD-aware bijective swizzle (528 % 8 == 0)
    const int w = (blockIdx.x & 7) * (NTILES / 8) + (blockIdx.x >> 3);

    int t = -1, m = 0, gstart = 0;
    {
        int accT = 0, accO = 0;
        for (int k = 0; k < TASKS; ++k) {
            const int c = cnt[k], nt = (c + BM - 1) >> 7;
            if (t < 0 && w < accT + nt) {
                t = k; gstart = accO + (w - accT) * BM;
                m = c - (w - accT) * BM; if (m > BM) m = BM;
            }
            accT += nt; accO += c;
        }
    }
    if (t < 0) return;

    const int tid = threadIdx.x;
    if (tid < BM) ridx[tid] = rowIdx[gstart + (tid < m ? tid : m - 1)];
    __syncthreads();

    const int lane = tid & 63, wv = tid >> 6;
    const int lg = lane >> 4, lr = lane & 15;
    const int wrow = (wv >> 1) * 64, wcol = (wv & 1) * 64;

    // A staging: instr j covers 4 rows (wv*32+j*4+lg), 16 lanes/row read 128B contiguous
    const float* gpA[8];
    unsigned wbA[8];
    #pragma unroll
    for (int j = 0; j < 8; ++j) {
        const int row = wv * 32 + j * 4 + lg;          // row & 3 == lg
        gpA[j] = x + ((size_t)ridx[row] << 10) + lr * 2;
        wbA[j] = row * 64 + (((lr >> 2) ^ lg) << 4) + (lr & 3) * 4;
    }
    // B staging: 2 x glds per wave, source sequential in pre-swizzled W1s
    const char* w1sT = (const char*)W1s + ((size_t)t << 18);
    const int bi = wv * 2;

    f32x2 a8[8];
    f32x4 acc[4][4] = {};
    const unsigned sw = (unsigned)((lg ^ (lr & 3)) << 4);   // fragment-read swizzle

    auto LOADA = [&](int kt) {
        #pragma unroll
        for (int j = 0; j < 8; ++j) a8[j] = *(const f32x2*)(gpA[j] + kt * 32);
    };
    auto WRITEA = [&](int buf) {
        char* ab = (char*)smem + buf * 16384;
        #pragma unroll
        for (int j = 0; j < 8; ++j) {
            unsigned pk = ((unsigned)f2bf(a8[j][1]) << 16) | (unsigned)f2bf(a8[j][0]);
            *(unsigned*)(ab + wbA[j]) = pk;
        }
    };
    auto ISSUEB = [&](int buf, int kt) {
        const char* src = w1sT + ((size_t)kt << 13) + bi * 1024 + lane * 16;
        char* dst = (char*)smem + buf * 16384 + 8192 + bi * 1024;
        glds16(src, dst);
        glds16(src + 1024, dst + 1024);
    };
    auto COMPUTE = [&](int buf) {
        const char* ab = (const char*)smem + buf * 16384;
        const char* bb = ab + 8192;
        bf16x8 af[4], bfr[4];
        #pragma unroll
        for (int rf = 0; rf < 4; ++rf)
            af[rf] = *(const bf16x8*)(ab + (wrow + rf * 16 + lr) * 64 + sw);
        #pragma unroll
        for (int cf = 0; cf < 4; ++cf)
            bfr[cf] = *(const bf16x8*)(bb + (wcol + cf * 16 + lr) * 64 + sw);
        #pragma unroll
        for (int rf = 0; rf < 4; ++rf)
            #pragma unroll
            for (int cf = 0; cf < 4; ++cf)
                acc[rf][cf] = __builtin_amdgcn_mfma_f32_16x16x32_bf16(af[rf], bfr[cf], acc[rf][cf], 0, 0, 0);
    };

    ISSUEB(0, 0);
    LOADA(0);
    WRITEA(0);
    __syncthreads();
    #pragma unroll 2
    for (int kt = 0; kt < 32; ++kt) {
        const int buf = kt & 1;
        if (kt < 31) { ISSUEB(buf ^ 1, kt + 1); LOADA(kt + 1); }
        COMPUTE(buf);
        if (kt < 31) WRITEA(buf ^ 1);
        __syncthreads();
    }

    // epilogue: bias + relu -> hl[128][256B] swizzled (reuses stage LDS)
    short* hl = smem;
    #pragma unroll
    for (int cf = 0; cf < 4; ++cf) {
        const int col = wcol + cf * 16 + lr;
        const float b1v = b1[t * HID + col];
        #pragma unroll
        for (int rf = 0; rf < 4; ++rf)
            #pragma unroll
            for (int q = 0; q < 4; ++q) {
                const int row = wrow + rf * 16 + lg * 4 + q;
                const float hv = fmaxf(acc[rf][cf][q] + b1v, 0.f);
                *(unsigned short*)((char*)hl + row * 256 +
                    (((col >> 3) ^ (row & 7)) << 4) + (col & 7) * 2) = f2bf(hv);
            }
    }
    __syncthreads();

    // GEMM2: [128 x 128] * [128 x 16]; wave wv owns rows wv*32..+32
    f32x4 acc2[2] = {};
    #pragma unroll
    for (int ks = 0; ks < 4; ++ks) {
        bf16x8 bvv = *(const bf16x8*)(W2t + (((size_t)t * 16 + lr) << 7) + ks * 32 + lg * 8);
        #pragma unroll
        for (int rf = 0; rf < 2; ++rf) {
            const int row = wv * 32 + rf * 16 + lr;
            bf16x8 avv = *(const bf16x8*)((const char*)hl + row * 256 +
                             (((ks * 4 + lg) ^ (row & 7)) << 4));
            acc2[rf] = __builtin_amdgcn_mfma_f32_16x16x32_bf16(avv, bvv, acc2[rf], 0, 0, 0);
        }
    }
    if (lr < NCLS) {
        const float b2v = b2[t * NCLS + lr];
        #pragma unroll
        for (int rf = 0; rf < 2; ++rf)
            #pragma unroll
            for (int q = 0; q < 4; ++q) {
                const int row = wv * 32 + rf * 16 + lg * 4 + q;
                if (row < m) out[(size_t)ridx[row] * NCLS + lr] = acc2[rf][q] + b2v;
            }
    }
}

extern "C" void kernel_launch(void* const* d_in, const int* in_sizes, int n_in,
                              void* d_out, int out_size, void* d_ws, size_t ws_size,
                              hipStream_t stream) {
    (void)in_sizes; (void)n_in; (void)out_size; (void)ws_size;
    const float* x       = (const float*)d_in[0];
    const int*   task_id = (const int*)d_in[1];
    const float* W1      = (const float*)d_in[2];
    const float* b1      = (const float*)d_in[3];
    const float* W2      = (const float*)d_in[4];
    const float* b2      = (const float*)d_in[5];
    float* out = (float*)d_out;
    int* ws = (int*)d_ws;
    hipMemsetAsync(ws, 0, 128, stream);               // cnt[16] + cursors[16]
    k_pre<<<784, 256, 0, stream>>>(task_id, W1, W2, ws);
    k_scatter<<<256, 256, 0, stream>>>(task_id, ws);
    k_main<<<NTILES, 256, 0, stream>>>(x, b1, b2, ws, out);
}

// Round 5
// 85.671 us; speedup vs baseline: 2.1380x; 1.0508x over previous
//
#include <hip/hip_runtime.h>
#include <hip/hip_bf16.h>

#define TASKS 16
#define DIM 1024
#define HID 128
#define NCLS 10
#define NB 65536
#define BM 128
#define NTILES (NB / BM + TASKS) // 528 = 8 * 66

typedef __attribute__((ext_vector_type(8))) short bf16x8;
typedef __attribute__((ext_vector_type(4))) float f32x4;
typedef __attribute__((ext_vector_type(2))) unsigned u32x2;

__device__ __forceinline__ unsigned short f2bf(float f) {
    union { __hip_bfloat16 h; unsigned short s; } u; u.h = __float2bfloat16(f); return u.s;
}

// async global->LDS, 16B/lane: dst is WAVE-UNIFORM base (HW adds lane*16), src per-lane
__device__ __forceinline__ void glds16(const void* gsrc, void* ldst) {
    __builtin_amdgcn_global_load_lds(
        (const __attribute__((address_space(1))) unsigned*)gsrc,
        (__attribute__((address_space(3))) unsigned*)ldst, 16, 0, 0);
}

// ws (ints): [0,16) cnt | [16,32) cursors | [64,64+NB) rowIdx
// shorts after: W1s [T][32 kstep][4096] bf16 swizzled-tile order (4MB), W2t [T][16][128] (64KB)

// ---- pass 0: zero cnt + cursors (kernel, not memset: keeps profile readable) ----
__global__ void k_zero(int* __restrict__ ws) {
    if (threadIdx.x < 32) ws[threadIdx.x] = 0;
}

// ---- pass 1: histogram + W1 -> swizzled bf16 tiles + W2 transpose ----
__global__ __launch_bounds__(256) void k_pre(const int* __restrict__ tid_arr,
                                             const float* __restrict__ W1,
                                             const float* __restrict__ W2,
                                             int* __restrict__ ws) {
    const int blk = blockIdx.x, tid = threadIdx.x;
    if (blk < 256) {                           // histogram
        __shared__ int l[TASKS];
        if (tid < TASKS) l[tid] = 0;
        __syncthreads();
        atomicAdd(&l[tid_arr[blk * 256 + tid]], 1);
        __syncthreads();
        if (tid < TASKS) atomicAdd(&ws[tid], l[tid]);
    } else if (blk < 768) {                    // W1 -> W1s: 8KB tile per (t, kstep), coalesced
        const int idx = blk - 256;             // [0,512)
        const int t = idx >> 5, kt = idx & 31;
        __shared__ float ld[32 * 132];         // [k][h] padded +4
        const float* src = W1 + ((size_t)t * DIM + kt * 32) * HID;
        #pragma unroll
        for (int r = 0; r < 16; ++r) {
            const int fl = r * 256 + tid;      // 0..4095 contiguous
            ld[(fl >> 7) * 132 + (fl & 127)] = src[fl];
        }
        __syncthreads();
        char* dst = (char*)((short*)(ws + 64 + NB) + ((size_t)(t * 32 + kt) << 12));
        const int col = tid >> 1, half = tid & 1;
        #pragma unroll
        for (int g = 0; g < 2; ++g) {
            const int lgk = (half * 2 + g) ^ (col & 3);   // baked XOR swizzle
            bf16x8 v;
            #pragma unroll
            for (int j = 0; j < 8; ++j)
                v[j] = (short)f2bf(ld[(lgk * 8 + j) * 132 + col]);
            *(bf16x8*)(dst + tid * 32 + g * 16) = v;      // sequential 32B/thread
        }
    } else {                                   // W2 [T][H][C] -> W2t [T][16][H] bf16
        const int t = blk - 768;
        short* W2t = (short*)(ws + 64 + NB) + ((size_t)TASKS * 32 * 4096);
        #pragma unroll
        for (int i = 0; i < 8; ++i) {
            const int o = i * 256 + tid, c = o >> 7, h = o & 127;
            const float v = (c < NCLS) ? W2[((size_t)t * HID + h) * NCLS + c] : 0.f;
            W2t[((size_t)t * 16 + c) * HID + h] = (short)f2bf(v);
        }
    }
}

// ---- pass 2: scatter row indices grouped by task ----
__global__ __launch_bounds__(256) void k_scatter(const int* __restrict__ tid_arr,
                                                 int* __restrict__ ws) {
    __shared__ int l[TASKS], base[TASKS], off[TASKS];
    const int tid = threadIdx.x;
    if (tid < TASKS) l[tid] = 0;
    __syncthreads();
    const int i = blockIdx.x * 256 + tid;
    const int t = tid_arr[i];
    const int rank = atomicAdd(&l[t], 1);
    __syncthreads();
    if (tid == 0) {
        int ro = 0;
        for (int k = 0; k < TASKS; ++k) { off[k] = ro; ro += ws[k]; }
    }
    if (tid < TASKS && l[tid] > 0) base[tid] = atomicAdd(&ws[16 + tid], l[tid]);
    __syncthreads();
    ws[64 + off[t] + base[t] + rank] = i;
}

// ---- pass 3: fused grouped GEMM, minimal-divergence staging ----
__global__ __launch_bounds__(256, 4) void k_main(
    const float* __restrict__ x, const float* __restrict__ b1,
    const float* __restrict__ b2, const int* __restrict__ ws,
    float* __restrict__ out)
{
    // [buf][A 8KB | B 8KB] x2 = 32KB; epilogue reuses as hl[128][256B]
    __shared__ __align__(16) short smem[16384];
    __shared__ int ridx[BM];

    const int* cnt = ws;
    const int* rowIdx = ws + 64;
    const short* W1s = (const short*)(ws + 64 + NB);
    const short* W2t = W1s + ((size_t)TASKS * 32 * 4096);

    // XCD-aware bijective swizzle (528 % 8 == 0)
    const int w = (blockIdx.x & 7) * (NTILES / 8) + (blockIdx.x >> 3);

    int t = -1, m = 0, gstart = 0;
    {
        int accT = 0, accO = 0;
        for (int k = 0; k < TASKS; ++k) {
            const int c = cnt[k], nt = (c + BM - 1) >> 7;
            if (t < 0 && w < accT + nt) {
                t = k; gstart = accO + (w - accT) * BM;
                m = c - (w - accT) * BM; if (m > BM) m = BM;
            }
            accT += nt; accO += c;
        }
    }
    if (t < 0) return;

    const int tid = threadIdx.x;
    if (tid < BM) ridx[tid] = rowIdx[gstart + (tid < m ? tid : m - 1)];
    __syncthreads();

    const int lane = tid & 63, wv = tid >> 6;
    const int lg = lane >> 4, lr = lane & 15;
    const int wrow = (wv >> 1) * 64, wcol = (wv & 1) * 64;

    // A staging: instr j covers 8 rows (wv*32+j*8+lane/8), 8 lanes/row x 16B = 128B/row
    const float* gpA[4];
    unsigned wbA[4];
    #pragma unroll
    for (int j = 0; j < 4; ++j) {
        const int row = wv * 32 + j * 8 + (lane >> 3);
        gpA[j] = x + ((size_t)ridx[row] << 10) + (lane & 7) * 4;
        wbA[j] = row * 64 + ((((lane & 7) >> 1) ^ (row & 3)) << 4) + (lane & 1) * 8;
    }
    // B staging: 2 x glds per wave, source sequential in pre-swizzled W1s
    const char* w1sT = (const char*)W1s + ((size_t)t << 18);
    const int bi = wv * 2;

    f32x4 a8[4];
    f32x4 acc[4][4] = {};
    const unsigned sw = (unsigned)((lg ^ (lr & 3)) << 4);   // fragment-read swizzle

    auto LOADA = [&](int kt) {
        #pragma unroll
        for (int j = 0; j < 4; ++j) a8[j] = *(const f32x4*)(gpA[j] + kt * 32);
    };
    auto WRITEA = [&](int buf) {
        char* ab = (char*)smem + buf * 16384;
        #pragma unroll
        for (int j = 0; j < 4; ++j) {
            u32x2 pk;
            pk[0] = ((unsigned)f2bf(a8[j][1]) << 16) | (unsigned)f2bf(a8[j][0]);
            pk[1] = ((unsigned)f2bf(a8[j][3]) << 16) | (unsigned)f2bf(a8[j][2]);
            *(u32x2*)(ab + wbA[j]) = pk;                    // ds_write_b64
        }
    };
    auto ISSUEB = [&](int buf, int kt) {
        const char* src = w1sT + ((size_t)kt << 13) + bi * 1024 + lane * 16;
        char* dst = (char*)smem + buf * 16384 + 8192 + bi * 1024;
        glds16(src, dst);
        glds16(src + 1024, dst + 1024);
    };
    auto COMPUTE = [&](int buf) {
        const char* ab = (const char*)smem + buf * 16384;
        const char* bb = ab + 8192;
        bf16x8 af[4], bfr[4];
        #pragma unroll
        for (int rf = 0; rf < 4; ++rf)
            af[rf] = *(const bf16x8*)(ab + (wrow + rf * 16 + lr) * 64 + sw);
        #pragma unroll
        for (int cf = 0; cf < 4; ++cf)
            bfr[cf] = *(const bf16x8*)(bb + (wcol + cf * 16 + lr) * 64 + sw);
        #pragma unroll
        for (int rf = 0; rf < 4; ++rf)
            #pragma unroll
            for (int cf = 0; cf < 4; ++cf)
                acc[rf][cf] = __builtin_amdgcn_mfma_f32_16x16x32_bf16(af[rf], bfr[cf], acc[rf][cf], 0, 0, 0);
    };

    ISSUEB(0, 0);
    LOADA(0);
    WRITEA(0);
    __syncthreads();
    #pragma unroll 2
    for (int kt = 0; kt < 32; ++kt) {
        const int buf = kt & 1;
        if (kt < 31) { ISSUEB(buf ^ 1, kt + 1); LOADA(kt + 1); }
        COMPUTE(buf);
        if (kt < 31) WRITEA(buf ^ 1);
        __syncthreads();
    }

    // epilogue: bias + relu -> hl[128][256B] swizzled (reuses stage LDS)
    short* hl = smem;
    #pragma unroll
    for (int cf = 0; cf < 4; ++cf) {
        const int col = wcol + cf * 16 + lr;
        const float b1v = b1[t * HID + col];
        #pragma unroll
        for (int rf = 0; rf < 4; ++rf)
            #pragma unroll
            for (int q = 0; q < 4; ++q) {
                const int row = wrow + rf * 16 + lg * 4 + q;
                const float hv = fmaxf(acc[rf][cf][q] + b1v, 0.f);
                *(unsigned short*)((char*)hl + row * 256 +
                    (((col >> 3) ^ (row & 7)) << 4) + (col & 7) * 2) = f2bf(hv);
            }
    }
    __syncthreads();

    // GEMM2: [128 x 128] * [128 x 16]; wave wv owns rows wv*32..+32
    f32x4 acc2[2] = {};
    #pragma unroll
    for (int ks = 0; ks < 4; ++ks) {
        bf16x8 bvv = *(const bf16x8*)(W2t + (((size_t)t * 16 + lr) << 7) + ks * 32 + lg * 8);
        #pragma unroll
        for (int rf = 0; rf < 2; ++rf) {
            const int row = wv * 32 + rf * 16 + lr;
            bf16x8 avv = *(const bf16x8*)((const char*)hl + row * 256 +
                             (((ks * 4 + lg) ^ (row & 7)) << 4));
            acc2[rf] = __builtin_amdgcn_mfma_f32_16x16x32_bf16(avv, bvv, acc2[rf], 0, 0, 0);
        }
    }
    if (lr < NCLS) {
        const float b2v = b2[t * NCLS + lr];
        #pragma unroll
        for (int rf = 0; rf < 2; ++rf)
            #pragma unroll
            for (int q = 0; q < 4; ++q) {
                const int row = wv * 32 + rf * 16 + lg * 4 + q;
                if (row < m) out[(size_t)ridx[row] * NCLS + lr] = acc2[rf][q] + b2v;
            }
    }
}

extern "C" void kernel_launch(void* const* d_in, const int* in_sizes, int n_in,
                              void* d_out, int out_size, void* d_ws, size_t ws_size,
                              hipStream_t stream) {
    (void)in_sizes; (void)n_in; (void)out_size; (void)ws_size;
    const float* x       = (const float*)d_in[0];
    const int*   task_id = (const int*)d_in[1];
    const float* W1      = (const float*)d_in[2];
    const float* b1      = (const float*)d_in[3];
    const float* W2      = (const float*)d_in[4];
    const float* b2      = (const float*)d_in[5];
    float* out = (float*)d_out;
    int* ws = (int*)d_ws;
    k_zero<<<1, 64, 0, stream>>>(ws);
    k_pre<<<784, 256, 0, stream>>>(task_id, W1, W2, ws);
    k_scatter<<<256, 256, 0, stream>>>(task_id, ws);
    k_main<<<NTILES, 256, 0, stream>>>(x, b1, b2, ws, out);
}

// Round 6
// 84.881 us; speedup vs baseline: 2.1579x; 1.0093x over previous
//
#include <hip/hip_runtime.h>
#include <hip/hip_bf16.h>

#define TASKS 16
#define DIM 1024
#define HID 128
#define NCLS 10
#define NB 65536
#define BM 128
#define NTILES (NB / BM + TASKS) // 528 = 8 * 66

// ws layout (ints):
//  [0, 4096)            per-block histogram partials [256 blk][16 task]
//  [4096, 4112)         per-task totals (written by k_scatter block 0)
//  [4160, 4160+NB)      rowIdx grouped by task
//  [69696, ...) shorts: W1s [T][32 kstep][4096] swizzled-tile bf16 (4MB), W2t [T][16][128]
#define WS_TOT  4096
#define WS_RIDX 4160
#define WS_W1S  (WS_RIDX + NB)   // 69696; byte offset 278784, 16B-aligned

typedef __attribute__((ext_vector_type(8))) short bf16x8;
typedef __attribute__((ext_vector_type(4))) float f32x4;
typedef __attribute__((ext_vector_type(2))) unsigned u32x2;

__device__ __forceinline__ unsigned short f2bf(float f) {
    union { __hip_bfloat16 h; unsigned short s; } u; u.h = __float2bfloat16(f); return u.s;
}

// async global->LDS, 16B/lane: dst is WAVE-UNIFORM base (HW adds lane*16), src per-lane
__device__ __forceinline__ void glds16(const void* gsrc, void* ldst) {
    __builtin_amdgcn_global_load_lds(
        (const __attribute__((address_space(1))) unsigned*)gsrc,
        (__attribute__((address_space(3))) unsigned*)ldst, 16, 0, 0);
}

// ---- pass 1: per-block histogram partials + W1 -> swizzled bf16 tiles + W2 transpose ----
__global__ __launch_bounds__(256) void k_pre(const int* __restrict__ tid_arr,
                                             const float* __restrict__ W1,
                                             const float* __restrict__ W2,
                                             int* __restrict__ ws) {
    const int blk = blockIdx.x, tid = threadIdx.x;
    if (blk < 256) {                           // histogram partials (plain stores, no zero/atomics)
        __shared__ int l[TASKS];
        if (tid < TASKS) l[tid] = 0;
        __syncthreads();
        atomicAdd(&l[tid_arr[blk * 256 + tid]], 1);
        __syncthreads();
        if (tid < TASKS) ws[blk * TASKS + tid] = l[tid];
    } else if (blk < 768) {                    // W1 -> W1s: 8KB tile per (t, kstep), coalesced
        const int idx = blk - 256;             // [0,512)
        const int t = idx >> 5, kt = idx & 31;
        __shared__ float ld[32 * 132];         // [k][h] padded +4
        const float* src = W1 + ((size_t)t * DIM + kt * 32) * HID;
        #pragma unroll
        for (int r = 0; r < 16; ++r) {
            const int fl = r * 256 + tid;      // 0..4095 contiguous
            ld[(fl >> 7) * 132 + (fl & 127)] = src[fl];
        }
        __syncthreads();
        char* dst = (char*)((short*)(ws + WS_W1S) + ((size_t)(t * 32 + kt) << 12));
        const int col = tid >> 1, half = tid & 1;
        #pragma unroll
        for (int g = 0; g < 2; ++g) {
            const int lgk = (half * 2 + g) ^ (col & 3);   // baked XOR swizzle
            bf16x8 v;
            #pragma unroll
            for (int j = 0; j < 8; ++j)
                v[j] = (short)f2bf(ld[(lgk * 8 + j) * 132 + col]);
            *(bf16x8*)(dst + tid * 32 + g * 16) = v;      // sequential 32B/thread
        }
    } else {                                   // W2 [T][H][C] -> W2t [T][16][H] bf16
        const int t = blk - 768;
        short* W2t = (short*)(ws + WS_W1S) + ((size_t)TASKS * 32 * 4096);
        #pragma unroll
        for (int i = 0; i < 8; ++i) {
            const int o = i * 256 + tid, c = o >> 7, h = o & 127;
            const float v = (c < NCLS) ? W2[((size_t)t * HID + h) * NCLS + c] : 0.f;
            W2t[((size_t)t * 16 + c) * HID + h] = (short)f2bf(v);
        }
    }
}

// ---- pass 2: deterministic scatter (bases from cross-block prefix of partials) ----
__global__ __launch_bounds__(256) void k_scatter(const int* __restrict__ tid_arr,
                                                 int* __restrict__ ws) {
    __shared__ int part[256 * TASKS];          // 16KB
    __shared__ int l[TASKS], offl[TASKS], prel[TASKS];
    const int b = blockIdx.x, tid = threadIdx.x;
    #pragma unroll
    for (int r = 0; r < 16; ++r) part[r * 256 + tid] = ws[r * 256 + tid];
    if (tid < TASKS) l[tid] = 0;
    __syncthreads();
    const int i = b * 256 + tid;
    const int t = tid_arr[i];
    const int rank = atomicAdd(&l[t], 1);      // LDS-only; order-independent output
    __syncthreads();
    if (tid < TASKS) {
        int pre = 0, tot = 0;
        for (int bb = 0; bb < 256; ++bb) {
            const int v = part[bb * TASKS + tid];
            if (bb < b) pre += v;
            tot += v;
        }
        prel[tid] = pre;
        part[tid] = tot;                       // reuse slots [0,16) for totals
        if (b == 0) ws[WS_TOT + tid] = tot;    // publish for k_main
    }
    __syncthreads();
    if (tid == 0) {
        int ro = 0;
        for (int k = 0; k < TASKS; ++k) { offl[k] = ro; ro += part[k]; }
    }
    __syncthreads();
    ws[WS_RIDX + offl[t] + prel[t] + rank] = i;
}

// ---- pass 3: fused grouped GEMM, minimal-divergence staging ----
__global__ __launch_bounds__(256, 4) void k_main(
    const float* __restrict__ x, const float* __restrict__ b1,
    const float* __restrict__ b2, const int* __restrict__ ws,
    float* __restrict__ out)
{
    // [buf][A 8KB | B 8KB] x2 = 32KB; epilogue reuses as hl[128][256B]
    __shared__ __align__(16) short smem[16384];
    __shared__ int ridx[BM];

    const int* tot = ws + WS_TOT;
    const int* rowIdx = ws + WS_RIDX;
    const short* W1s = (const short*)(ws + WS_W1S);
    const short* W2t = W1s + ((size_t)TASKS * 32 * 4096);

    // XCD-aware bijective swizzle (528 % 8 == 0)
    const int w = (blockIdx.x & 7) * (NTILES / 8) + (blockIdx.x >> 3);

    int t = -1, m = 0, gstart = 0;
    {
        int accT = 0, accO = 0;
        for (int k = 0; k < TASKS; ++k) {
            const int c = tot[k], nt = (c + BM - 1) >> 7;
            if (t < 0 && w < accT + nt) {
                t = k; gstart = accO + (w - accT) * BM;
                m = c - (w - accT) * BM; if (m > BM) m = BM;
            }
            accT += nt; accO += c;
        }
    }
    if (t < 0) return;

    const int tid = threadIdx.x;
    if (tid < BM) ridx[tid] = rowIdx[gstart + (tid < m ? tid : m - 1)];
    __syncthreads();

    const int lane = tid & 63, wv = tid >> 6;
    const int lg = lane >> 4, lr = lane & 15;
    const int wrow = (wv >> 1) * 64, wcol = (wv & 1) * 64;

    // A staging: instr j covers 8 rows (wv*32+j*8+lane/8), 8 lanes/row x 16B = 128B/row
    const float* gpA[4];
    unsigned wbA[4];
    #pragma unroll
    for (int j = 0; j < 4; ++j) {
        const int row = wv * 32 + j * 8 + (lane >> 3);
        gpA[j] = x + ((size_t)ridx[row] << 10) + (lane & 7) * 4;
        wbA[j] = row * 64 + ((((lane & 7) >> 1) ^ (row & 3)) << 4) + (lane & 1) * 8;
    }
    // B staging: 2 x glds per wave, source sequential in pre-swizzled W1s
    const char* w1sT = (const char*)W1s + ((size_t)t << 18);
    const int bi = wv * 2;

    f32x4 a8[4];
    f32x4 acc[4][4] = {};
    const unsigned sw = (unsigned)((lg ^ (lr & 3)) << 4);   // fragment-read swizzle

    auto LOADA = [&](int kt) {
        #pragma unroll
        for (int j = 0; j < 4; ++j) a8[j] = *(const f32x4*)(gpA[j] + kt * 32);
    };
    auto WRITEA = [&](int buf) {
        char* ab = (char*)smem + buf * 16384;
        #pragma unroll
        for (int j = 0; j < 4; ++j) {
            u32x2 pk;
            pk[0] = ((unsigned)f2bf(a8[j][1]) << 16) | (unsigned)f2bf(a8[j][0]);
            pk[1] = ((unsigned)f2bf(a8[j][3]) << 16) | (unsigned)f2bf(a8[j][2]);
            *(u32x2*)(ab + wbA[j]) = pk;                    // ds_write_b64
        }
    };
    auto ISSUEB = [&](int buf, int kt) {
        const char* src = w1sT + ((size_t)kt << 13) + bi * 1024 + lane * 16;
        char* dst = (char*)smem + buf * 16384 + 8192 + bi * 1024;
        glds16(src, dst);
        glds16(src + 1024, dst + 1024);
    };
    auto COMPUTE = [&](int buf) {
        const char* ab = (const char*)smem + buf * 16384;
        const char* bb = ab + 8192;
        bf16x8 af[4], bfr[4];
        #pragma unroll
        for (int rf = 0; rf < 4; ++rf)
            af[rf] = *(const bf16x8*)(ab + (wrow + rf * 16 + lr) * 64 + sw);
        #pragma unroll
        for (int cf = 0; cf < 4; ++cf)
            bfr[cf] = *(const bf16x8*)(bb + (wcol + cf * 16 + lr) * 64 + sw);
        #pragma unroll
        for (int rf = 0; rf < 4; ++rf)
            #pragma unroll
            for (int cf = 0; cf < 4; ++cf)
                acc[rf][cf] = __builtin_amdgcn_mfma_f32_16x16x32_bf16(af[rf], bfr[cf], acc[rf][cf], 0, 0, 0);
    };

    ISSUEB(0, 0);
    LOADA(0);
    WRITEA(0);
    __syncthreads();
    #pragma unroll 2
    for (int kt = 0; kt < 32; ++kt) {
        const int buf = kt & 1;
        if (kt < 31) { ISSUEB(buf ^ 1, kt + 1); LOADA(kt + 1); }
        COMPUTE(buf);
        if (kt < 31) WRITEA(buf ^ 1);
        __syncthreads();
    }

    // epilogue: bias + relu -> hl[128][256B] swizzled (reuses stage LDS)
    short* hl = smem;
    #pragma unroll
    for (int cf = 0; cf < 4; ++cf) {
        const int col = wcol + cf * 16 + lr;
        const float b1v = b1[t * HID + col];
        #pragma unroll
        for (int rf = 0; rf < 4; ++rf)
            #pragma unroll
            for (int q = 0; q < 4; ++q) {
                const int row = wrow + rf * 16 + lg * 4 + q;
                const float hv = fmaxf(acc[rf][cf][q] + b1v, 0.f);
                *(unsigned short*)((char*)hl + row * 256 +
                    (((col >> 3) ^ (row & 7)) << 4) + (col & 7) * 2) = f2bf(hv);
            }
    }
    __syncthreads();

    // GEMM2: [128 x 128] * [128 x 16]; wave wv owns rows wv*32..+32
    f32x4 acc2[2] = {};
    #pragma unroll
    for (int ks = 0; ks < 4; ++ks) {
        bf16x8 bvv = *(const bf16x8*)(W2t + (((size_t)t * 16 + lr) << 7) + ks * 32 + lg * 8);
        #pragma unroll
        for (int rf = 0; rf < 2; ++rf) {
            const int row = wv * 32 + rf * 16 + lr;
            bf16x8 avv = *(const bf16x8*)((const char*)hl + row * 256 +
                             (((ks * 4 + lg) ^ (row & 7)) << 4));
            acc2[rf] = __builtin_amdgcn_mfma_f32_16x16x32_bf16(avv, bvv, acc2[rf], 0, 0, 0);
        }
    }
    if (lr < NCLS) {
        const float b2v = b2[t * NCLS + lr];
        #pragma unroll
        for (int rf = 0; rf < 2; ++rf)
            #pragma unroll
            for (int q = 0; q < 4; ++q) {
                const int row = wv * 32 + rf * 16 + lg * 4 + q;
                if (row < m) out[(size_t)ridx[row] * NCLS + lr] = acc2[rf][q] + b2v;
            }
    }
}

extern "C" void kernel_launch(void* const* d_in, const int* in_sizes, int n_in,
                              void* d_out, int out_size, void* d_ws, size_t ws_size,
                              hipStream_t stream) {
    (void)in_sizes; (void)n_in; (void)out_size; (void)ws_size;
    const float* x       = (const float*)d_in[0];
    const int*   task_id = (const int*)d_in[1];
    const float* W1      = (const float*)d_in[2];
    const float* b1      = (const float*)d_in[3];
    const float* W2      = (const float*)d_in[4];
    const float* b2      = (const float*)d_in[5];
    float* out = (float*)d_out;
    int* ws = (int*)d_ws;
    k_pre<<<784, 256, 0, stream>>>(task_id, W1, W2, ws);
    k_scatter<<<256, 256, 0, stream>>>(task_id, ws);
    k_main<<<NTILES, 256, 0, stream>>>(x, b1, b2, ws, out);
}

// Round 7
// 82.799 us; speedup vs baseline: 2.2122x; 1.0251x over previous
//
#include <hip/hip_runtime.h>
#include <hip/hip_bf16.h>

#define TASKS 16
#define DIM 1024
#define HID 128
#define NCLS 10
#define NB 65536
#define BM 128
#define NTILES (NB / BM + TASKS) // 528 = 8 * 66

// ws layout (ints):
//  [0, 4096)            per-block histogram partials [256 blk][16 task]
//  [4096, 4112)         per-task totals (written by k_scatter block 0)
//  [4160, 4160+NB)      rowIdx grouped by task
//  [69696, ...) shorts: W1s [T][32 kstep][4096] swizzled-tile bf16 (4MB), W2t [T][16][128]
#define WS_TOT  4096
#define WS_RIDX 4160
#define WS_W1S  (WS_RIDX + NB)   // 69696; byte offset 278784, 16B-aligned

typedef __attribute__((ext_vector_type(8))) short bf16x8;
typedef __attribute__((ext_vector_type(4))) float f32x4;
typedef __attribute__((ext_vector_type(2))) unsigned u32x2;

__device__ __forceinline__ unsigned short f2bf(float f) {
    union { __hip_bfloat16 h; unsigned short s; } u; u.h = __float2bfloat16(f); return u.s;
}

// async global->LDS, 16B/lane: dst is WAVE-UNIFORM base (HW adds lane*16), src per-lane
__device__ __forceinline__ void glds16(const void* gsrc, void* ldst) {
    __builtin_amdgcn_global_load_lds(
        (const __attribute__((address_space(1))) unsigned*)gsrc,
        (__attribute__((address_space(3))) unsigned*)ldst, 16, 0, 0);
}

// ---- pass 1: per-block histogram partials + W1 -> swizzled bf16 tiles + W2 transpose ----
__global__ __launch_bounds__(256) void k_pre(const int* __restrict__ tid_arr,
                                             const float* __restrict__ W1,
                                             const float* __restrict__ W2,
                                             int* __restrict__ ws) {
    const int blk = blockIdx.x, tid = threadIdx.x;
    if (blk < 256) {                           // histogram partials (plain stores, no zero/atomics)
        __shared__ int l[TASKS];
        if (tid < TASKS) l[tid] = 0;
        __syncthreads();
        atomicAdd(&l[tid_arr[blk * 256 + tid]], 1);
        __syncthreads();
        if (tid < TASKS) ws[blk * TASKS + tid] = l[tid];
    } else if (blk < 768) {                    // W1 -> W1s: 8KB tile per (t, kstep), coalesced
        const int idx = blk - 256;             // [0,512)
        const int t = idx >> 5, kt = idx & 31;
        __shared__ float ld[32 * 132];         // [k][h] padded +4
        const float* src = W1 + ((size_t)t * DIM + kt * 32) * HID;
        #pragma unroll
        for (int r = 0; r < 16; ++r) {
            const int fl = r * 256 + tid;      // 0..4095 contiguous
            ld[(fl >> 7) * 132 + (fl & 127)] = src[fl];
        }
        __syncthreads();
        char* dst = (char*)((short*)(ws + WS_W1S) + ((size_t)(t * 32 + kt) << 12));
        const int col = tid >> 1, half = tid & 1;
        #pragma unroll
        for (int g = 0; g < 2; ++g) {
            const int lgk = (half * 2 + g) ^ (col & 3);   // baked XOR swizzle
            bf16x8 v;
            #pragma unroll
            for (int j = 0; j < 8; ++j)
                v[j] = (short)f2bf(ld[(lgk * 8 + j) * 132 + col]);
            *(bf16x8*)(dst + tid * 32 + g * 16) = v;      // sequential 32B/thread
        }
    } else {                                   // W2 [T][H][C] -> W2t [T][16][H] bf16
        const int t = blk - 768;
        short* W2t = (short*)(ws + WS_W1S) + ((size_t)TASKS * 32 * 4096);
        #pragma unroll
        for (int i = 0; i < 8; ++i) {
            const int o = i * 256 + tid, c = o >> 7, h = o & 127;
            const float v = (c < NCLS) ? W2[((size_t)t * HID + h) * NCLS + c] : 0.f;
            W2t[((size_t)t * 16 + c) * HID + h] = (short)f2bf(v);
        }
    }
}

// ---- pass 2: deterministic scatter (bases from cross-block prefix of partials) ----
__global__ __launch_bounds__(256) void k_scatter(const int* __restrict__ tid_arr,
                                                 int* __restrict__ ws) {
    __shared__ int part[256 * TASKS];          // 16KB
    __shared__ int l[TASKS], offl[TASKS], prel[TASKS];
    const int b = blockIdx.x, tid = threadIdx.x;
    #pragma unroll
    for (int r = 0; r < 16; ++r) part[r * 256 + tid] = ws[r * 256 + tid];
    if (tid < TASKS) l[tid] = 0;
    __syncthreads();
    const int i = b * 256 + tid;
    const int t = tid_arr[i];
    const int rank = atomicAdd(&l[t], 1);      // LDS-only; order-independent output
    __syncthreads();
    if (tid < TASKS) {
        int pre = 0, tot = 0;
        for (int bb = 0; bb < 256; ++bb) {
            const int v = part[bb * TASKS + tid];
            if (bb < b) pre += v;
            tot += v;
        }
        prel[tid] = pre;
        part[tid] = tot;                       // reuse slots [0,16) for totals
        if (b == 0) ws[WS_TOT + tid] = tot;    // publish for k_main
    }
    __syncthreads();
    if (tid == 0) {
        int ro = 0;
        for (int k = 0; k < TASKS; ++k) { offl[k] = ro; ro += part[k]; }
    }
    __syncthreads();
    ws[WS_RIDX + offl[t] + prel[t] + rank] = i;
}

// ---- pass 3: fused grouped GEMM, counted-vmcnt pipeline (T4) ----
__global__ __launch_bounds__(256, 4) void k_main(
    const float* __restrict__ x, const float* __restrict__ b1,
    const float* __restrict__ b2, const int* __restrict__ ws,
    float* __restrict__ out)
{
    // [buf][A 8KB | B 8KB] x2 = 32KB; epilogue reuses as hl[128][256B]
    __shared__ __align__(16) short smem[16384];
    __shared__ int ridx[BM];

    const int* tot = ws + WS_TOT;
    const int* rowIdx = ws + WS_RIDX;
    const short* W1s = (const short*)(ws + WS_W1S);
    const short* W2t = W1s + ((size_t)TASKS * 32 * 4096);

    // XCD-aware bijective swizzle (528 % 8 == 0)
    const int w = (blockIdx.x & 7) * (NTILES / 8) + (blockIdx.x >> 3);

    int t = -1, m = 0, gstart = 0;
    {
        int accT = 0, accO = 0;
        for (int k = 0; k < TASKS; ++k) {
            const int c = tot[k], nt = (c + BM - 1) >> 7;
            if (t < 0 && w < accT + nt) {
                t = k; gstart = accO + (w - accT) * BM;
                m = c - (w - accT) * BM; if (m > BM) m = BM;
            }
            accT += nt; accO += c;
        }
    }
    if (t < 0) return;

    const int tid = threadIdx.x;
    if (tid < BM) ridx[tid] = rowIdx[gstart + (tid < m ? tid : m - 1)];
    __syncthreads();

    const int lane = tid & 63, wv = tid >> 6;
    const int lg = lane >> 4, lr = lane & 15;
    const int wrow = (wv >> 1) * 64, wcol = (wv & 1) * 64;

    // A staging: instr j covers 8 rows (wv*32+j*8+lane/8), 8 lanes/row x 16B = 128B/row
    const float* gpA[4];
    unsigned wbA[4];
    #pragma unroll
    for (int j = 0; j < 4; ++j) {
        const int row = wv * 32 + j * 8 + (lane >> 3);
        gpA[j] = x + ((size_t)ridx[row] << 10) + (lane & 7) * 4;
        wbA[j] = row * 64 + ((((lane & 7) >> 1) ^ (row & 3)) << 4) + (lane & 1) * 8;
    }
    // B staging: 2 x glds per wave, source sequential in pre-swizzled W1s
    const char* w1sT = (const char*)W1s + ((size_t)t << 18);
    const int bi = wv * 2;

    f32x4 a8[4];
    f32x4 acc[4][4] = {};
    const unsigned sw = (unsigned)((lg ^ (lr & 3)) << 4);   // fragment-read swizzle

    auto LOADA = [&](int kt) {
        #pragma unroll
        for (int j = 0; j < 4; ++j) a8[j] = *(const f32x4*)(gpA[j] + kt * 32);
    };
    auto WRITEA = [&](int buf) {
        char* ab = (char*)smem + buf * 16384;
        #pragma unroll
        for (int j = 0; j < 4; ++j) {
            u32x2 pk;
            pk[0] = ((unsigned)f2bf(a8[j][1]) << 16) | (unsigned)f2bf(a8[j][0]);
            pk[1] = ((unsigned)f2bf(a8[j][3]) << 16) | (unsigned)f2bf(a8[j][2]);
            *(u32x2*)(ab + wbA[j]) = pk;                    // ds_write_b64
        }
    };
    auto ISSUEB = [&](int buf, int kt) {
        const char* src = w1sT + ((size_t)kt << 13) + bi * 1024 + lane * 16;
        char* dst = (char*)smem + buf * 16384 + 8192 + bi * 1024;
        glds16(src, dst);
        glds16(src + 1024, dst + 1024);
    };
    auto COMPUTE = [&](int buf) {
        const char* ab = (const char*)smem + buf * 16384;
        const char* bb = ab + 8192;
        bf16x8 af[4], bfr[4];
        #pragma unroll
        for (int rf = 0; rf < 4; ++rf)
            af[rf] = *(const bf16x8*)(ab + (wrow + rf * 16 + lr) * 64 + sw);
        #pragma unroll
        for (int cf = 0; cf < 4; ++cf)
            bfr[cf] = *(const bf16x8*)(bb + (wcol + cf * 16 + lr) * 64 + sw);
        #pragma unroll
        for (int rf = 0; rf < 4; ++rf)
            #pragma unroll
            for (int cf = 0; cf < 4; ++cf)
                acc[rf][cf] = __builtin_amdgcn_mfma_f32_16x16x32_bf16(af[rf], bfr[cf], acc[rf][cf], 0, 0, 0);
    };

    // prologue: tile0 staged; tile1 A-regs loaded; g0 drained before barrier
    LOADA(0);                 // A0 (4 vmem)
    ISSUEB(0, 0);             // g0 (2 glds)
    WRITEA(0);                // waits A0 (oldest) -> g0 may stay in flight
    LOADA(1);                 // in-flight: [g0(2), A1(4)]
    asm volatile("s_waitcnt vmcnt(4) lgkmcnt(0)" ::: "memory");   // drain g0 + ds_writes
    __builtin_amdgcn_s_barrier();
    __builtin_amdgcn_sched_barrier(0);

    // steady state invariant at the counted wait: in-flight = [g_{kt+1}(2), A_{kt+2}(4)]
    // -> vmcnt(4) drains exactly g_{kt+1}; A_{kt+2} crosses the barrier in flight.
    #pragma unroll 2
    for (int kt = 0; kt < 32; ++kt) {
        const int buf = kt & 1;
        ISSUEB(buf ^ 1, kt + 1 < 32 ? kt + 1 : 31);   // clamp keeps vmcnt counts uniform
        WRITEA(buf ^ 1);                              // tile kt+1 regs -> LDS
        LOADA(kt + 2 < 32 ? kt + 2 : 31);
        COMPUTE(buf);
        asm volatile("s_waitcnt vmcnt(4) lgkmcnt(0)" ::: "memory");
        __builtin_amdgcn_s_barrier();
        __builtin_amdgcn_sched_barrier(0);
    }
    __syncthreads();   // full drain (incl. clamped junk loads) before LDS reuse

    // epilogue: bias + relu -> hl[128][256B] swizzled (reuses stage LDS)
    short* hl = smem;
    #pragma unroll
    for (int cf = 0; cf < 4; ++cf) {
        const int col = wcol + cf * 16 + lr;
        const float b1v = b1[t * HID + col];
        #pragma unroll
        for (int rf = 0; rf < 4; ++rf)
            #pragma unroll
            for (int q = 0; q < 4; ++q) {
                const int row = wrow + rf * 16 + lg * 4 + q;
                const float hv = fmaxf(acc[rf][cf][q] + b1v, 0.f);
                *(unsigned short*)((char*)hl + row * 256 +
                    (((col >> 3) ^ (row & 7)) << 4) + (col & 7) * 2) = f2bf(hv);
            }
    }
    __syncthreads();

    // GEMM2: [128 x 128] * [128 x 16]; wave wv owns rows wv*32..+32
    f32x4 acc2[2] = {};
    #pragma unroll
    for (int ks = 0; ks < 4; ++ks) {
        bf16x8 bvv = *(const bf16x8*)(W2t + (((size_t)t * 16 + lr) << 7) + ks * 32 + lg * 8);
        #pragma unroll
        for (int rf = 0; rf < 2; ++rf) {
            const int row = wv * 32 + rf * 16 + lr;
            bf16x8 avv = *(const bf16x8*)((const char*)hl + row * 256 +
                             (((ks * 4 + lg) ^ (row & 7)) << 4));
            acc2[rf] = __builtin_amdgcn_mfma_f32_16x16x32_bf16(avv, bvv, acc2[rf], 0, 0, 0);
        }
    }
    if (lr < NCLS) {
        const float b2v = b2[t * NCLS + lr];
        #pragma unroll
        for (int rf = 0; rf < 2; ++rf)
            #pragma unroll
            for (int q = 0; q < 4; ++q) {
                const int row = wv * 32 + rf * 16 + lg * 4 + q;
                if (row < m) out[(size_t)ridx[row] * NCLS + lr] = acc2[rf][q] + b2v;
            }
    }
}

extern "C" void kernel_launch(void* const* d_in, const int* in_sizes, int n_in,
                              void* d_out, int out_size, void* d_ws, size_t ws_size,
                              hipStream_t stream) {
    (void)in_sizes; (void)n_in; (void)out_size; (void)ws_size;
    const float* x       = (const float*)d_in[0];
    const int*   task_id = (const int*)d_in[1];
    const float* W1      = (const float*)d_in[2];
    const float* b1      = (const float*)d_in[3];
    const float* W2      = (const float*)d_in[4];
    const float* b2      = (const float*)d_in[5];
    float* out = (float*)d_out;
    int* ws = (int*)d_ws;
    k_pre<<<784, 256, 0, stream>>>(task_id, W1, W2, ws);
    k_scatter<<<256, 256, 0, stream>>>(task_id, ws);
    k_main<<<NTILES, 256, 0, stream>>>(x, b1, b2, ws, out);
}